// Round 9
// baseline (79.930 us; speedup 1.0000x reference)
//
#include <hip/hip_runtime.h>
#include <stdint.h>

typedef unsigned long long u64;
typedef unsigned int u32;
typedef __attribute__((ext_vector_type(8))) short bf16x8;
typedef __attribute__((ext_vector_type(16))) float f32x16;

__device__ __forceinline__ u64 fkey(float f, unsigned idx) {
    unsigned u = __float_as_uint(f);
    u = (u & 0x80000000u) ? ~u : (u | 0x80000000u);
    return ((u64)u << 32) | (u64)idx;
}
__device__ __forceinline__ u64 umin64(u64 a, u64 b) { return a < b ? a : b; }
__device__ __forceinline__ unsigned short f2bf(float f) {   // RNE fp32->bf16
    unsigned u = __float_as_uint(f);
    return (unsigned short)((u + 0x7FFFu + ((u >> 16) & 1u)) >> 16);
}
__device__ __forceinline__ float bf2f(unsigned short b) {
    return __uint_as_float((unsigned)b << 16);
}

// ---------------------------------------------------------------------------
// Kernel 1 (unchanged, proven): split x into bf16 planes, stored LINEAR:
// Xs[row][plane][chunk][col64]; col64 = par*32 + (colin&31),
// colin = (p*48+q)*4 + (j&3), chunk = colin>>5. Swizzle applied ONCE by gemm's
// per-lane global_load_lds source offset. Also xsum_lo/hi and scoreboard init.
// ---------------------------------------------------------------------------
extern "C" __global__ __launch_bounds__(256)
void prep_kernel(const float* __restrict__ x, unsigned short* __restrict__ Xs,
                 float* __restrict__ xsum, u64* __restrict__ sb) {
    __shared__ float xbuf[768];
    const int row = blockIdx.x;          // 0..255
    const int a = row >> 4, i = row & 15;
    for (int pass = 0; pass < 3; ++pass) {
        int t = pass * 256 + threadIdx.x;          // 0..767
        int g = t >> 3, j = t & 7;
        int p = g / 48, q = g - 48 * p;
        float v = x[((size_t)(a * 2 + p) * 126 + (19 + q)) * 128 + (i * 8 + j)];
        xbuf[t] = v;
        unsigned short b1 = f2bf(v);
        unsigned short b2 = f2bf(v - bf2f(b1));
        int par = (j >> 2);                        // 0 = lo, 1 = hi
        int colin = g * 4 + (j & 3);               // 0..383 within parity
        int c = colin >> 5;                        // chunk 0..11
        int col64 = par * 32 + (colin & 31);       // 0..63 within chunk-row
        size_t base = (size_t)row * 1536 + c * 64 + col64;
        Xs[base] = b1;            // plane 0 (x1)
        Xs[base + 768] = b2;      // plane 1 (x2)
    }
    __syncthreads();
    if (threadIdx.x < 2) {
        int off = threadIdx.x ? 4 : 0;
        float s = 0.f;
        for (int g = 0; g < 96; ++g)
            for (int j = 0; j < 4; ++j)
                s += xbuf[g * 8 + off + j];
        xsum[threadIdx.x * 256 + row] = s;
    }
    if (row == 0) {
        for (int t = threadIdx.x; t < 368; t += 256) sb[t] = ~0ULL;
    }
}

// ---------------------------------------------------------------------------
// Kernel 2: 32x32x16 MFMA GEMM. Block = 64 ent x 256 rows, 256 threads
// (4 waves), wave tile 64x64 (m2 x n2), grid 512, 2 blocks/CU (LDS 80KB).
// cb staging = r5's PROVEN unit geometry (entry se, group sgl, half shalf):
// each 16B load is one parity-pure j-quad, placed at LDS col shalf*32+sgl*4
// (deinterleaved, matches Xs layout), granule-swizzled by ^(se&7). 256
// threads x 2 units (u=tid, tid+256; same parity): entries se0,+16,+32,+48.
// Stats: per-thread sp/sq[4] at parity tid&1; shfl masks 2/4/8 reduce over
// groups preserving parity; writers (tid&15)<2.
// MFMA: par2 x ks2 x m2 x n2 x 4 split products. A/B k-map self-consistent.
// D layout (m74/m101): col = lane&31 (x-row), ent = (reg&3)+8*(reg>>2)+4*l5.
// Epilogue: exact u64-key argmin -> LDS scoreboard -> 368 global atomicMin.
// ---------------------------------------------------------------------------
extern "C" __global__ __launch_bounds__(256, 2)
void gemm_kernel(const float* __restrict__ cb, const unsigned short* __restrict__ Xs,
                 const float* __restrict__ xsum, u64* __restrict__ sb) {
    __shared__ __align__(16) unsigned short cbt[128][64];   // 16KB: row = plane*64+ent
    __shared__ __align__(16) unsigned short xst[512][64];   // 64KB: row = plane*256+xrow

    const int tid = threadIdx.x;        // 0..255
    const int lane = tid & 63;
    const int wid = tid >> 6;           // 0..3
    const int k0 = blockIdx.x * 64;
    const int rb = wid * 64;            // wave row base
    const int l31 = lane & 31;
    const int l5 = lane >> 5;           // 0/1
    const int h7 = lane & 7;

    // cb staging unit (r5 geometry): se0 = tid>>4 (0..15; unit2 adds +16),
    // sgl = (tid>>1)&7, shalf = tid&1. Both units share sgl/shalf/(se&7).
    const int se0 = tid >> 4;
    const int sgl = (tid >> 1) & 7;
    const int shalf = tid & 1;
    const int ssw = (((shalf * 32 + sgl * 4) >> 3) ^ (se0 & 7)) * 8 + (sgl & 1) * 4;

    // X source swizzle: source granule = (lane&7) ^ (ldsrow&7), ldsrow&7 == lane>>3
    const int gswz = h7 ^ (lane >> 3);

    f32x16 acc[2][2][2] = {};           // [parity][m][n]
    float sp[4] = {0.f, 0.f, 0.f, 0.f}; // entries se0, se0+32, se0+16, se0+48
    float sq[4] = {0.f, 0.f, 0.f, 0.f};

    for (int c = 0; c < 12; ++c) {
        __syncthreads();
        // ---- stage cb: 4 entries x one parity-quad each -> split -> LDS
        {
            const float* s1 = cb + (size_t)(k0 + se0) * 768 + (c * 8 + sgl) * 8 + shalf * 4;
            float4 v1 = *(const float4*)s1;              // entry se0
            float4 v2 = *(const float4*)(s1 + 32 * 768); // entry se0+32
            float4 v3 = *(const float4*)(s1 + 16 * 768); // entry se0+16
            float4 v4 = *(const float4*)(s1 + 48 * 768); // entry se0+48
            sp[0] += v1.x + v1.y + v1.z + v1.w;
            sq[0] += v1.x * v1.x + v1.y * v1.y + v1.z * v1.z + v1.w * v1.w;
            sp[1] += v2.x + v2.y + v2.z + v2.w;
            sq[1] += v2.x * v2.x + v2.y * v2.y + v2.z * v2.z + v2.w * v2.w;
            sp[2] += v3.x + v3.y + v3.z + v3.w;
            sq[2] += v3.x * v3.x + v3.y * v3.y + v3.z * v3.z + v3.w * v3.w;
            sp[3] += v4.x + v4.y + v4.z + v4.w;
            sq[3] += v4.x * v4.x + v4.y * v4.y + v4.z * v4.z + v4.w * v4.w;
            unsigned short a1x = f2bf(v1.x), a1y = f2bf(v1.y), a1z = f2bf(v1.z), a1w = f2bf(v1.w);
            unsigned short a2x = f2bf(v2.x), a2y = f2bf(v2.y), a2z = f2bf(v2.z), a2w = f2bf(v2.w);
            unsigned short a3x = f2bf(v3.x), a3y = f2bf(v3.y), a3z = f2bf(v3.z), a3w = f2bf(v3.w);
            unsigned short a4x = f2bf(v4.x), a4y = f2bf(v4.y), a4z = f2bf(v4.z), a4w = f2bf(v4.w);
            *(ushort4*)&cbt[se0][ssw]       = make_ushort4(a1x, a1y, a1z, a1w);
            *(ushort4*)&cbt[se0 + 64][ssw]  = make_ushort4(f2bf(v1.x - bf2f(a1x)), f2bf(v1.y - bf2f(a1y)),
                                                           f2bf(v1.z - bf2f(a1z)), f2bf(v1.w - bf2f(a1w)));
            *(ushort4*)&cbt[se0 + 32][ssw]  = make_ushort4(a2x, a2y, a2z, a2w);
            *(ushort4*)&cbt[se0 + 96][ssw]  = make_ushort4(f2bf(v2.x - bf2f(a2x)), f2bf(v2.y - bf2f(a2y)),
                                                           f2bf(v2.z - bf2f(a2z)), f2bf(v2.w - bf2f(a2w)));
            *(ushort4*)&cbt[se0 + 16][ssw]  = make_ushort4(a3x, a3y, a3z, a3w);
            *(ushort4*)&cbt[se0 + 80][ssw]  = make_ushort4(f2bf(v3.x - bf2f(a3x)), f2bf(v3.y - bf2f(a3y)),
                                                           f2bf(v3.z - bf2f(a3z)), f2bf(v3.w - bf2f(a3w)));
            *(ushort4*)&cbt[se0 + 48][ssw]  = make_ushort4(a4x, a4y, a4z, a4w);
            *(ushort4*)&cbt[se0 + 112][ssw] = make_ushort4(f2bf(v4.x - bf2f(a4x)), f2bf(v4.y - bf2f(a4y)),
                                                           f2bf(v4.z - bf2f(a4z)), f2bf(v4.w - bf2f(a4w)));
        }
        // ---- stage X: 64KB via global_load_lds (per-lane swizzled source)
#pragma unroll
        for (int i = 0; i < 16; ++i) {
            int lrow = (wid << 7) + (i << 3) + (lane >> 3);   // 0..511
            const unsigned short* gs = Xs + (size_t)(lrow & 255) * 1536
                                          + (lrow >> 8) * 768 + c * 64 + gswz * 8;
            __builtin_amdgcn_global_load_lds(
                (const __attribute__((address_space(1))) u32*)gs,
                (__attribute__((address_space(3))) u32*)&xst[(wid << 7) + (i << 3)][0],
                16, 0, 0);
        }
        __syncthreads();
        // ---- MFMA: par2 x ks2, frags m2 x n2, 4 split products (K=16 each)
#pragma unroll
        for (int par = 0; par < 2; ++par) {
#pragma unroll
            for (int ks = 0; ks < 2; ++ks) {
                const int sws = ((par * 4 + ks * 2 + l5) ^ h7) * 8;
                bf16x8 A1[2], A2[2], B1[2], B2[2];
#pragma unroll
                for (int m = 0; m < 2; ++m) {
                    A1[m] = *(const bf16x8*)&cbt[m * 32 + l31][sws];
                    A2[m] = *(const bf16x8*)&cbt[m * 32 + l31 + 64][sws];
                }
#pragma unroll
                for (int n = 0; n < 2; ++n) {
                    B1[n] = *(const bf16x8*)&xst[rb + n * 32 + l31][sws];
                    B2[n] = *(const bf16x8*)&xst[rb + n * 32 + l31 + 256][sws];
                }
#pragma unroll
                for (int m = 0; m < 2; ++m)
#pragma unroll
                    for (int n = 0; n < 2; ++n) {
                        acc[par][m][n] = __builtin_amdgcn_mfma_f32_32x32x16_bf16(A1[m], B1[n], acc[par][m][n], 0, 0, 0);
                        acc[par][m][n] = __builtin_amdgcn_mfma_f32_32x32x16_bf16(A2[m], B1[n], acc[par][m][n], 0, 0, 0);
                        acc[par][m][n] = __builtin_amdgcn_mfma_f32_32x32x16_bf16(A1[m], B2[n], acc[par][m][n], 0, 0, 0);
                        acc[par][m][n] = __builtin_amdgcn_mfma_f32_32x32x16_bf16(A2[m], B2[n], acc[par][m][n], 0, 0, 0);
                    }
            }
        }
    }

    // ---- finalize stats: reduce over groups (masks 2,4,8 keep parity bit0)
#pragma unroll
    for (int m = 2; m <= 8; m <<= 1)
#pragma unroll
        for (int s = 0; s < 4; ++s) {
            sp[s] += __shfl_xor(sp[s], m);
            sq[s] += __shfl_xor(sq[s], m);
        }
    __syncthreads();                    // all MFMA-phase ds_reads done; cbt dead
    float* stf = (float*)&cbt[0][0];    // [par*128 + {0:csum,64:csq} + ent]
    u64* msb = (u64*)((char*)&cbt[0][0] + 1024);   // 368-entry LDS scoreboard
    if ((tid & 15) < 2) {
        const int p = tid & 1;
        const int eo[4] = {0, 32, 16, 48};
#pragma unroll
        for (int s = 0; s < 4; ++s) {
            stf[p * 128 + se0 + eo[s]]      = sp[s];
            stf[p * 128 + 64 + se0 + eo[s]] = sq[s];
        }
    }
    for (int t = tid; t < 368; t += 256) msb[t] = ~0ULL;
    __syncthreads();

    // ---- scoring + argmin. D: col = l31 (x-row), ent = (reg&3)+8*(reg>>2)+4*l5
#pragma unroll
    for (int n = 0; n < 2; ++n) {
        const int r = rb + n * 32 + l31;
        const int i_ = r & 15;
        const int a_ = r >> 4;
        const float xl = xsum[r], xh = xsum[256 + r];
        u64 kA = ~0ULL, kB = ~0ULL;
#pragma unroll
        for (int m = 0; m < 2; ++m) {
#pragma unroll
            for (int reg = 0; reg < 16; ++reg) {
                const int el = m * 32 + (reg & 3) + 8 * (reg >> 2) + 4 * l5;
                const unsigned kg = (unsigned)(k0 + el);
                float stl = stf[el],       sql = stf[64 + el];
                float sth = stf[128 + el], sqh = stf[192 + el];
                float dl = acc[0][m][n][reg], dh = acc[1][m][n][reg];
                float lo_d = sql - 2.f * dl;
                float lo_m = (384.f - 2.f * stl + sql) - 2.f * (xl - dl);
                float hi_d = sqh - 2.f * dh;
                float hi_m = (384.f - 2.f * sth + sqh) - 2.f * (xh - dh);
                if (i_ < 7) {
                    kA = umin64(kA, umin64(fkey(lo_d, kg), fkey(lo_m, kg + 32768u)));
                    kB = umin64(kB, umin64(fkey(hi_d, kg), fkey(hi_m, kg + 32768u)));
                } else {
                    kA = umin64(kA, umin64(fkey(lo_d + hi_d, kg), fkey(lo_m + hi_m, kg + 32768u)));
                }
            }
        }
        kA = umin64(kA, __shfl_xor(kA, 32));
        kB = umin64(kB, __shfl_xor(kB, 32));
        if (lane < 32) {
            if (i_ < 7) {
                atomicMin(&msb[a_ * 23 + i_], kA);
                atomicMin(&msb[a_ * 23 + 7 + i_], kB);
            } else {
                atomicMin(&msb[a_ * 23 + 14 + (i_ - 7)], kA);
            }
        }
    }
    __syncthreads();
    for (int t = tid; t < 368; t += 256) atomicMin(&sb[t], msb[t]);
}

// ---------------------------------------------------------------------------
// Kernel 3: emit bits. out[a][0:6]=0; bit b: stream s=b/22, bit bb=b%22.
// ---------------------------------------------------------------------------
extern "C" __global__ __launch_bounds__(512)
void bits_kernel(const u64* __restrict__ sb, float* __restrict__ out) {
    const int a = blockIdx.x;
    const int pos = threadIdx.x;   // 0..511
    float v = 0.f;
    if (pos >= 6) {
        int b = pos - 6;
        int s = b / 22;
        int bb = b - s * 22;
        unsigned idx = (unsigned)(sb[a * 23 + s] & 0xFFFFFFFFu);
        v = (float)((idx >> bb) & 1u);
    }
    out[a * 512 + pos] = v;
}

extern "C" void kernel_launch(void* const* d_in, const int* in_sizes, int n_in,
                              void* d_out, int out_size, void* d_ws, size_t ws_size,
                              hipStream_t stream) {
    const float* x  = (const float*)d_in[0];   // [16,2,126,128]
    const float* cb = (const float*)d_in[1];   // [32768,2,48,8]
    char* ws = (char*)d_ws;
    unsigned short* Xs = (unsigned short*)ws;              // 256*1536 bf16 = 768KB
    float* xsum        = (float*)(ws + 786432);            // 512 f32
    u64*   sb          = (u64*)(ws + 788480);              // 368 u64
    float* out = (float*)d_out;

    prep_kernel<<<256, 256, 0, stream>>>(x, Xs, xsum, sb);
    gemm_kernel<<<512, 256, 0, stream>>>(cb, Xs, xsum, sb);
    bits_kernel<<<16, 512, 0, stream>>>(sb, out);
}